// Round 14
// baseline (143.841 us; speedup 1.0000x reference)
//
#include <hip/hip_runtime.h>
#include <hip/hip_bf16.h>

// SpatialLinearAttention: b=2,f=16,h=w=64,c=256, heads=8, D=32
// BF=32 fused batch, n=4096, hD=256.
// out[n,c] = sum_hd softmax_d(xWq)[n,hd] * W2[hd,c]
// W2[hd,c] = sum_e (ctx[h,d,e]/den[h,d]) * Wo[h*32+e,c]
// ctx[h,d,e] = sum_n exp(xWk)[n,h*32+d] * (xWv)[n,h*32+e];  den = sum_n exp(xWk)
// k1w: fused kv-proj + ctx. SINGLE slab buffer (72 KB LDS -> 2 blocks/CU);
//      2 barriers/strip, drains hidden by the sibling block. Slab stride 40, no XOR.
// k3s: fused q-proj + softmax + @W2t (unchanged from r13).

typedef __attribute__((ext_vector_type(8))) short bf16x8;
typedef __attribute__((ext_vector_type(4))) float f32x4;

__device__ __forceinline__ unsigned short f2bf(float x) {
  __hip_bfloat16 h = __float2bfloat16(x);          // HW v_cvt (RNE), 1 VALU op
  union { __hip_bfloat16 b; unsigned short u; } c; c.b = h; return c.u;
}

// ---------------- K0: transpose & convert weights to [N][K] bf16 ----------------
__global__ __launch_bounds__(256) void k0_prep(const float* __restrict__ Wq,
                                               const float* __restrict__ Wk,
                                               const float* __restrict__ Wv,
                                               unsigned short* __restrict__ WqT,
                                               unsigned short* __restrict__ WkvT) {
  int r = blockIdx.x, c = threadIdx.x;
  if (r < 256)      WqT [(r      )*256 + c] = f2bf(Wq[c*256 + r]);
  else if (r < 512) WkvT[(r - 256)*256 + c] = f2bf(Wk[c*256 + (r-256)]);
  else              WkvT[(r - 256)*256 + c] = f2bf(Wv[c*256 + (r-512)]);
}

// ---------------- K1w: fused kv-proj GEMM + exp + ctx reduction ----------------
// Grid 512 x 1024thr (16 waves). Wave w owns cols [w*32, w*32+32) of [Ek|V]
// (w<8: Ek logits+exp, w>=8: V). 8 strips of 32 rows.
// Single slab (stride 40, no XOR) -> 72 KB LDS -> 2 blocks/CU (32 waves/CU).
// Per strip: [stage As(t+1) | slab-write(t)] BAR [pf(t+2) | ctx(t) | main(t+1)] BAR.
__global__ __launch_bounds__(1024, 4) void k1w(const float* __restrict__ x,
                                               const unsigned short* __restrict__ WkvT,
                                               float* __restrict__ ctxp) {
  __shared__ unsigned short As[2][32*256];    // 16 KB each, swizzled (32 slots/row)
  __shared__ unsigned short slab[512*40];     // 40 KB: C^T [c][n], padded, single buf
  int bid = blockIdx.x;
  size_t rowbase = (size_t)bid * 256;
  int tid = threadIdx.x;
  int lane = tid & 63, w = tid >> 6;
  int cl = lane & 15, rq = (lane >> 4) << 2, fs = lane >> 4;
  int h = w & 7;
  bool isV = w >= 8;

  // ---- B fragments in registers: rows w*32..w*32+32 of WkvT ----
  bf16x8 bfr[2][8];
#pragma unroll
  for (int ni = 0; ni < 2; ++ni)
#pragma unroll
    for (int kk = 0; kk < 8; ++kk)
      bfr[ni][kk] = *(const bf16x8*)(WkvT + (size_t)(w*32 + ni*16 + cl)*256 + kk*32 + fs*8);

  // ---- ctx accumulators: head h, e-half per wave ----
  f32x4 c2[2] = {};
  float dena0 = 0.f, dena1 = 0.f;            // den partials (w<8 only)

  // ---- A staging map: 1024 thr = 32 rows x 32 slots ----
  int ar = tid >> 5, as_ = tid & 31;
  int aw = ar*256 + ((as_ ^ (ar & 7)) << 3);
  const float* ap = x + (rowbase + ar)*256 + as_*8;

  // slab read addrs for ctx (constant), stride 40, no XOR
  int ca0 = h*32 + cl, ca1 = h*32 + 16 + cl;
  int cb  = 256 + h*32 + (isV ? 16 : 0) + cl;
  int ra0 = ca0*40 + fs*8;
  int ra1 = ca1*40 + fs*8;
  int rb  = cb*40  + fs*8;

  f32x4 acc[2][2];

  auto stageA = [&](int buf, float4 v0, float4 v1) {
    unsigned short* Ab = &As[buf][0];
    union { ushort4 u4[2]; int4 i4; } pk;
    pk.u4[0].x = f2bf(v0.x); pk.u4[0].y = f2bf(v0.y); pk.u4[0].z = f2bf(v0.z); pk.u4[0].w = f2bf(v0.w);
    pk.u4[1].x = f2bf(v1.x); pk.u4[1].y = f2bf(v1.y); pk.u4[1].z = f2bf(v1.z); pk.u4[1].w = f2bf(v1.w);
    *(int4*)(&Ab[aw]) = pk.i4;
  };
  auto mainMFMA = [&](int buf) {
    unsigned short* Ab = &As[buf][0];
#pragma unroll
    for (int m = 0; m < 2; ++m)
#pragma unroll
      for (int ni = 0; ni < 2; ++ni) acc[m][ni] = (f32x4){};
#pragma unroll
    for (int kk = 0; kk < 8; ++kk) {
      int so = (((kk*4 + fs) ^ (cl & 7)) << 3);
      bf16x8 a0 = *(const bf16x8*)(&Ab[cl*256 + so]);
      bf16x8 a1 = *(const bf16x8*)(&Ab[(16 + cl)*256 + so]);
#pragma unroll
      for (int ni = 0; ni < 2; ++ni) {
        acc[0][ni] = __builtin_amdgcn_mfma_f32_16x16x32_bf16(a0, bfr[ni][kk], acc[0][ni], 0, 0, 0);
        acc[1][ni] = __builtin_amdgcn_mfma_f32_16x16x32_bf16(a1, bfr[ni][kk], acc[1][ni], 0, 0, 0);
      }
    }
  };
  auto slabWrite = [&]() {
#pragma unroll
    for (int ni = 0; ni < 2; ++ni) {
      int c = w*32 + ni*16 + cl;
#pragma unroll
      for (int m = 0; m < 2; ++m) {
        int n4 = m*16 + rq;
        ushort4 wv;
        if (!isV) {
          float e0 = __expf(acc[m][ni][0]), e1 = __expf(acc[m][ni][1]);
          float e2 = __expf(acc[m][ni][2]), e3 = __expf(acc[m][ni][3]);
          if (ni == 0) dena0 += (e0 + e1) + (e2 + e3); else dena1 += (e0 + e1) + (e2 + e3);
          wv.x = f2bf(e0); wv.y = f2bf(e1); wv.z = f2bf(e2); wv.w = f2bf(e3);
        } else {
          wv.x = f2bf(acc[m][ni][0]); wv.y = f2bf(acc[m][ni][1]);
          wv.z = f2bf(acc[m][ni][2]); wv.w = f2bf(acc[m][ni][3]);
        }
        *(ushort4*)(&slab[c*40 + n4]) = wv;
      }
    }
  };
  auto ctxMFMA = [&]() {
    bf16x8 af0 = *(const bf16x8*)(&slab[ra0]);
    bf16x8 af1 = *(const bf16x8*)(&slab[ra1]);
    bf16x8 bv  = *(const bf16x8*)(&slab[rb]);
    c2[0] = __builtin_amdgcn_mfma_f32_16x16x32_bf16(af0, bv, c2[0], 0, 0, 0);
    c2[1] = __builtin_amdgcn_mfma_f32_16x16x32_bf16(af1, bv, c2[1], 0, 0, 0);
  };

  // ---- prologue: stage strip 0, prefetch strip 1, main(0) ----
  float4 pa0 = *(const float4*)ap;
  float4 pa1 = *(const float4*)(ap + 4);
  stageA(0, pa0, pa1);
  {
    const float* apn = ap + 32*256;
    pa0 = *(const float4*)apn;
    pa1 = *(const float4*)(apn + 4);
  }
  __syncthreads();
  mainMFMA(0);

  // ---- main loop: 2 barriers/strip, 2 blocks/CU interleave the drains ----
  for (int t = 0; t < 8; ++t) {
    if (t < 7) stageA((t + 1) & 1, pa0, pa1);
    slabWrite();                             // acc(t) -> slab (+exp/den)
    __syncthreads();
    if (t < 6) {
      const float* apn = ap + (size_t)(t + 2)*32*256;
      pa0 = *(const float4*)apn;
      pa1 = *(const float4*)(apn + 4);
    }
    ctxMFMA();                               // reads slab(t)
    if (t < 7) mainMFMA((t + 1) & 1);        // acc(t+1)
    __syncthreads();                         // slab free for t+1
  }

  // ---- store partials: ctxp[bid][h][d*33 + e], den at e=32 ----
  float* cp = ctxp + ((size_t)bid*8 + h)*1056;
  int ec = isV ? 16 + cl : cl;
#pragma unroll
  for (int di = 0; di < 2; ++di)
#pragma unroll
    for (int r = 0; r < 4; ++r)
      cp[(di*16 + rq + r)*33 + ec] = c2[di][r];
  if (!isV) {
    dena0 += __shfl_xor(dena0, 16); dena0 += __shfl_xor(dena0, 32);
    dena1 += __shfl_xor(dena1, 16); dena1 += __shfl_xor(dena1, 32);
    if (fs == 0) {
      cp[cl*33 + 32]        = dena0;
      cp[(16 + cl)*33 + 32] = dena1;
    }
  }
}

// ---------------- K2b: W2t[bf][c][hd] = sum_e (ctx/den) * Wo ----------------
__global__ __launch_bounds__(256) void k2b_w2(const float* __restrict__ ctxp,
                                              const float* __restrict__ Wo,
                                              unsigned short* __restrict__ W2t) {
  __shared__ float clds[32*33];
  int bid = blockIdx.x;                    // bf*8 + h
  int h = bid & 7, bfi = bid >> 3;
  int tid = threadIdx.x;                   // = c
  for (int i = tid; i < 1056; i += 256) {
    float s = 0.f;
#pragma unroll
    for (int p = 0; p < 16; ++p)
      s += ctxp[((size_t)(bfi*16 + p)*8 + h)*1056 + i];
    clds[i] = s;
  }
  __syncthreads();
  float acc[32] = {};
#pragma unroll 4
  for (int e = 0; e < 32; ++e) {
    float w = Wo[(size_t)(h*32 + e)*256 + tid];
#pragma unroll
    for (int d = 0; d < 32; ++d) acc[d] += clds[d*33 + e] * w;
  }
  unsigned short* o = W2t + ((size_t)bfi*256 + tid)*256 + h*32;
#pragma unroll
  for (int d = 0; d < 32; ++d) o[d] = f2bf(acc[d] / clds[d*33 + 32]);
}

// ---------------- K3s: fused q-proj -> softmax_d -> @W2t -> out ----------------
// Grid 512 x 512thr, 256 rows/block, 8 strips of 32 rows, 1 barrier/strip.
// P1/P2 operand-swapped; prefetch issued post-barrier. (unchanged from r13)
__global__ __launch_bounds__(512, 2) void k3s(const float* __restrict__ x,
                                              const unsigned short* __restrict__ WqT,
                                              const unsigned short* __restrict__ W2t,
                                              float* __restrict__ out) {
  __shared__ unsigned short As[2][32*256];   // 16 KB each, swizzled (32 slots/row)
  __shared__ unsigned short Qs[2][32*256];   // 16 KB each, swizzled
  int bid = blockIdx.x;
  size_t rowbase = (size_t)bid * 256;
  int bfi = bid >> 4;                        // 16 blocks per bf
  int tid = threadIdx.x;
  int lane = tid & 63, wid = tid >> 6;
  int cl = lane & 15, rq = (lane >> 4) << 2, fs = lane >> 4;

  // ---- B panels in registers ----
  bf16x8 bq[2][8], bw[2][8];
#pragma unroll
  for (int nf = 0; nf < 2; ++nf)
#pragma unroll
    for (int kk = 0; kk < 8; ++kk) {
      bq[nf][kk] = *(const bf16x8*)(WqT + (size_t)(wid*32 + nf*16 + cl)*256 + kk*32 + fs*8);
      bw[nf][kk] = *(const bf16x8*)(W2t + ((size_t)bfi*256 + wid*32 + nf*16 + cl)*256 + kk*32 + fs*8);
    }

  int ar = tid >> 5, as_ = tid & 31;
  int aw0 = ar*256 + ((as_ ^ (ar & 7)) << 3);
  int aw1 = (16 + ar)*256 + ((as_ ^ (ar & 7)) << 3);
  const float* ap = x + (rowbase + ar)*256 + as_*8;

  int qslotbase = wid*4 + (rq >> 3);         // + nf*2
  ushort4 qpk[2][2];

  auto stageA = [&](int buf, float4 v0, float4 v1, float4 v2, float4 v3) {
    unsigned short* Ab = &As[buf][0];
    union { ushort4 u4[2]; int4 i4; } pk;
    pk.u4[0].x = f2bf(v0.x); pk.u4[0].y = f2bf(v0.y); pk.u4[0].z = f2bf(v0.z); pk.u4[0].w = f2bf(v0.w);
    pk.u4[1].x = f2bf(v1.x); pk.u4[1].y = f2bf(v1.y); pk.u4[1].z = f2bf(v1.z); pk.u4[1].w = f2bf(v1.w);
    *(int4*)(&Ab[aw0]) = pk.i4;
    pk.u4[0].x = f2bf(v2.x); pk.u4[0].y = f2bf(v2.y); pk.u4[0].z = f2bf(v2.z); pk.u4[0].w = f2bf(v2.w);
    pk.u4[1].x = f2bf(v3.x); pk.u4[1].y = f2bf(v3.y); pk.u4[1].z = f2bf(v3.z); pk.u4[1].w = f2bf(v3.w);
    *(int4*)(&Ab[aw1]) = pk.i4;
  };
  auto p1soft = [&](int buf) {
    unsigned short* Ab = &As[buf][0];
    f32x4 ql[2][2] = {};
#pragma unroll
    for (int kk = 0; kk < 8; ++kk) {
      int so = (((kk*4 + fs) ^ (cl & 7)) << 3);
      bf16x8 a0 = *(const bf16x8*)(&Ab[cl*256 + so]);
      bf16x8 a1 = *(const bf16x8*)(&Ab[(16 + cl)*256 + so]);
#pragma unroll
      for (int nf = 0; nf < 2; ++nf) {
        ql[0][nf] = __builtin_amdgcn_mfma_f32_16x16x32_bf16(bq[nf][kk], a0, ql[0][nf], 0, 0, 0);
        ql[1][nf] = __builtin_amdgcn_mfma_f32_16x16x32_bf16(bq[nf][kk], a1, ql[1][nf], 0, 0, 0);
      }
    }
#pragma unroll
    for (int m = 0; m < 2; ++m) {
      float e0[4], e1[4]; float s8 = 0.f;
#pragma unroll
      for (int r = 0; r < 4; ++r) { e0[r] = __expf(ql[m][0][r]); e1[r] = __expf(ql[m][1][r]); s8 += e0[r] + e1[r]; }
      float s = s8; s += __shfl_xor(s, 16); s += __shfl_xor(s, 32);
      float inv = 1.0f / s;
      qpk[m][0].x = f2bf(e0[0]*inv); qpk[m][0].y = f2bf(e0[1]*inv); qpk[m][0].z = f2bf(e0[2]*inv); qpk[m][0].w = f2bf(e0[3]*inv);
      qpk[m][1].x = f2bf(e1[0]*inv); qpk[m][1].y = f2bf(e1[1]*inv); qpk[m][1].z = f2bf(e1[2]*inv); qpk[m][1].w = f2bf(e1[3]*inv);
    }
  };
  auto qwrite = [&](int buf) {
    unsigned short* Qb = &Qs[buf][0];
#pragma unroll
    for (int m = 0; m < 2; ++m) {
      int row = m*16 + cl;
#pragma unroll
      for (int nf = 0; nf < 2; ++nf) {
        int slot = qslotbase + nf*2;
        *(ushort4*)(&Qb[row*256 + ((slot ^ (row & 7)) << 3) + (rq & 4)]) = qpk[m][nf];
      }
    }
  };

  float4 pa0 = *(const float4*)ap;
  float4 pa1 = *(const float4*)(ap + 4);
  float4 pa2 = *(const float4*)(ap + 16*256);
  float4 pa3 = *(const float4*)(ap + 16*256 + 4);
  stageA(0, pa0, pa1, pa2, pa3);
  {
    const float* apn = ap + 32*256;
    pa0 = *(const float4*)apn;
    pa1 = *(const float4*)(apn + 4);
    pa2 = *(const float4*)(apn + 16*256);
    pa3 = *(const float4*)(apn + 16*256 + 4);
  }
  __syncthreads();
  p1soft(0);

  for (int t = 0; t < 7; ++t) {
    // pre-bar: stage As(t+1) from regs, write Qs(t)
    stageA((t + 1) & 1, pa0, pa1, pa2, pa3);
    qwrite(t & 1);
    __syncthreads();
    // post-bar: issue prefetch(t+2) first (drained only at NEXT barrier)
    if (t < 6) {
      const float* apn = ap + (size_t)(t + 2)*32*256;
      pa0 = *(const float4*)apn;
      pa1 = *(const float4*)(apn + 4);
      pa2 = *(const float4*)(apn + 16*256);
      pa3 = *(const float4*)(apn + 16*256 + 4);
    }
    // P2(t)
    f32x4 oa[2][2] = {};
    {
      unsigned short* Qb = &Qs[t & 1][0];
#pragma unroll
      for (int kk = 0; kk < 8; ++kk) {
        int so = (((kk*4 + fs) ^ (cl & 7)) << 3);
        bf16x8 q0 = *(const bf16x8*)(&Qb[cl*256 + so]);
        bf16x8 q1 = *(const bf16x8*)(&Qb[(16 + cl)*256 + so]);
#pragma unroll
        for (int nf = 0; nf < 2; ++nf) {
          oa[0][nf] = __builtin_amdgcn_mfma_f32_16x16x32_bf16(bw[nf][kk], q0, oa[0][nf], 0, 0, 0);
          oa[1][nf] = __builtin_amdgcn_mfma_f32_16x16x32_bf16(bw[nf][kk], q1, oa[1][nf], 0, 0, 0);
        }
      }
    }
    // P1(t+1) + softmax(t+1)
    p1soft((t + 1) & 1);
    // out(t): float4 stores
#pragma unroll
    for (int m = 0; m < 2; ++m)
#pragma unroll
      for (int nf = 0; nf < 2; ++nf)
        *(f32x4*)(&out[(rowbase + (size_t)t*32 + m*16 + cl)*256 + wid*32 + nf*16 + rq]) = oa[m][nf];
  }
  // ---- tail: strip 7 ----
  qwrite(1);
  __syncthreads();
  {
    unsigned short* Qb = &Qs[1][0];
    f32x4 oa[2][2] = {};
#pragma unroll
    for (int kk = 0; kk < 8; ++kk) {
      int so = (((kk*4 + fs) ^ (cl & 7)) << 3);
      bf16x8 q0 = *(const bf16x8*)(&Qb[cl*256 + so]);
      bf16x8 q1 = *(const bf16x8*)(&Qb[(16 + cl)*256 + so]);
#pragma unroll
      for (int nf = 0; nf < 2; ++nf) {
        oa[0][nf] = __builtin_amdgcn_mfma_f32_16x16x32_bf16(bw[nf][kk], q0, oa[0][nf], 0, 0, 0);
        oa[1][nf] = __builtin_amdgcn_mfma_f32_16x16x32_bf16(bw[nf][kk], q1, oa[1][nf], 0, 0, 0);
      }
    }
#pragma unroll
    for (int m = 0; m < 2; ++m)
#pragma unroll
      for (int nf = 0; nf < 2; ++nf)
        *(f32x4*)(&out[(rowbase + (size_t)7*32 + m*16 + cl)*256 + wid*32 + nf*16 + rq]) = oa[m][nf];
  }
}

extern "C" void kernel_launch(void* const* d_in, const int* in_sizes, int n_in,
                              void* d_out, int out_size, void* d_ws, size_t ws_size,
                              hipStream_t stream) {
  const float* x  = (const float*)d_in[0];
  const float* Wq = (const float*)d_in[1];
  const float* Wk = (const float*)d_in[2];
  const float* Wv = (const float*)d_in[3];
  const float* Wo = (const float*)d_in[4];
  float* out = (float*)d_out;

  // ws layout: WkvT (131072 ush) | WqT (65536 ush) | W2t (2097152 ush) | ctxp (512*8*1056 f32)
  unsigned short* WkvT = (unsigned short*)d_ws;
  unsigned short* WqT  = WkvT + 131072;
  unsigned short* W2t  = WqT  + 65536;
  float*          ctxp = (float*)(W2t + 2097152);

  k0_prep <<<768,  256,  0, stream>>>(Wq, Wk, Wv, WqT, WkvT);
  k1w     <<<512,  1024, 0, stream>>>(x, WkvT, ctxp);
  k2b_w2  <<<256,  256,  0, stream>>>(ctxp, Wo, W2t);
  k3s     <<<512,  512,  0, stream>>>(x, WqT, W2t, out);
}

// Round 15
// 138.683 us; speedup vs baseline: 1.0372x; 1.0372x over previous
//
#include <hip/hip_runtime.h>
#include <hip/hip_bf16.h>

// SpatialLinearAttention: b=2,f=16,h=w=64,c=256, heads=8, D=32
// BF=32 fused batch, n=4096, hD=256.
// out[n,c] = sum_hd softmax_d(xWq)[n,hd] * W2[hd,c]
// W2[hd,c] = sum_e (ctx[h,d,e]/den[h,d]) * Wo[h*32+e,c]
// ctx[h,d,e] = sum_n exp(xWk)[n,h*32+d] * (xWv)[n,h*32+e];  den = sum_n exp(xWk)
// k1w: r13 structure (dbuf slab stride 40 no-XOR, 1 bar/strip, post-bar prefetch)
//      + asm-pinned B-fragments (defeats compiler remat: VGPR 64 showed bfr was
//      being re-loaded from L2 every strip instead of staying in registers).
// k3s: unchanged from r13.

typedef __attribute__((ext_vector_type(8))) short bf16x8;
typedef __attribute__((ext_vector_type(4))) float f32x4;

__device__ __forceinline__ unsigned short f2bf(float x) {
  __hip_bfloat16 h = __float2bfloat16(x);          // HW v_cvt (RNE), 1 VALU op
  union { __hip_bfloat16 b; unsigned short u; } c; c.b = h; return c.u;
}

// ---------------- K0: transpose & convert weights to [N][K] bf16 ----------------
__global__ __launch_bounds__(256) void k0_prep(const float* __restrict__ Wq,
                                               const float* __restrict__ Wk,
                                               const float* __restrict__ Wv,
                                               unsigned short* __restrict__ WqT,
                                               unsigned short* __restrict__ WkvT) {
  int r = blockIdx.x, c = threadIdx.x;
  if (r < 256)      WqT [(r      )*256 + c] = f2bf(Wq[c*256 + r]);
  else if (r < 512) WkvT[(r - 256)*256 + c] = f2bf(Wk[c*256 + (r-256)]);
  else              WkvT[(r - 256)*256 + c] = f2bf(Wv[c*256 + (r-512)]);
}

// ---------------- K1w: fused kv-proj GEMM + exp + ctx reduction ----------------
// Grid 512 x 1024thr (16 waves). Wave w owns cols [w*32, w*32+32) of [Ek|V]
// (w<8: Ek logits+exp, w>=8: V). 8 strips of 32 rows, 1 barrier/strip.
// Slab [c][n] stride 40 ushorts, no XOR. B-frags PINNED in VGPRs via inline asm.
__global__ __launch_bounds__(1024, 4) void k1w(const float* __restrict__ x,
                                               const unsigned short* __restrict__ WkvT,
                                               float* __restrict__ ctxp) {
  __shared__ unsigned short As[2][32*256];    // 16 KB each, swizzled (32 slots/row)
  __shared__ unsigned short slab[2][512*40];  // 40 KB each: C^T [c][n], padded
  int bid = blockIdx.x;
  size_t rowbase = (size_t)bid * 256;
  int tid = threadIdx.x;
  int lane = tid & 63, w = tid >> 6;
  int cl = lane & 15, rq = (lane >> 4) << 2, fs = lane >> 4;
  int h = w & 7;
  bool isV = w >= 8;

  // ---- B fragments in registers: rows w*32..w*32+32 of WkvT ----
  bf16x8 bfr[2][8];
#pragma unroll
  for (int ni = 0; ni < 2; ++ni)
#pragma unroll
    for (int kk = 0; kk < 8; ++kk)
      bfr[ni][kk] = *(const bf16x8*)(WkvT + (size_t)(w*32 + ni*16 + cl)*256 + kk*32 + fs*8);
  // PIN: opaque asm makes each fragment's def point un-rematerializable, forcing
  // true register residency across the strip loop (compiler was re-loading from
  // L2 every strip at VGPR_Count=64).
#pragma unroll
  for (int ni = 0; ni < 2; ++ni)
#pragma unroll
    for (int kk = 0; kk < 8; ++kk)
      asm volatile("" : "+v"(bfr[ni][kk]));

  // ---- ctx accumulators: head h, e-half per wave ----
  f32x4 c2[2] = {};
  float dena0 = 0.f, dena1 = 0.f;            // den partials (w<8 only)

  // ---- A staging map: 1024 thr = 32 rows x 32 slots ----
  int ar = tid >> 5, as_ = tid & 31;
  int aw = ar*256 + ((as_ ^ (ar & 7)) << 3);
  const float* ap = x + (rowbase + ar)*256 + as_*8;

  // slab read addrs for ctx (constant), stride 40, no XOR: fs picks 8-n slot
  int ca0 = h*32 + cl, ca1 = h*32 + 16 + cl;
  int cb  = 256 + h*32 + (isV ? 16 : 0) + cl;
  int ra0 = ca0*40 + fs*8;
  int ra1 = ca1*40 + fs*8;
  int rb  = cb*40  + fs*8;

  f32x4 acc[2][2];

  // ---- prologue: stage strip 0, prefetch strip 1 ----
  float4 pa0 = *(const float4*)ap;
  float4 pa1 = *(const float4*)(ap + 4);
  {
    unsigned short* Ab = &As[0][0];
    union { ushort4 u4[2]; int4 i4; } pk;
    pk.u4[0].x = f2bf(pa0.x); pk.u4[0].y = f2bf(pa0.y); pk.u4[0].z = f2bf(pa0.z); pk.u4[0].w = f2bf(pa0.w);
    pk.u4[1].x = f2bf(pa1.x); pk.u4[1].y = f2bf(pa1.y); pk.u4[1].z = f2bf(pa1.z); pk.u4[1].w = f2bf(pa1.w);
    *(int4*)(&Ab[aw]) = pk.i4;
  }
  {
    const float* apn = ap + 32*256;
    pa0 = *(const float4*)apn;
    pa1 = *(const float4*)(apn + 4);
  }
  __syncthreads();
  // main MFMA strip 0
  {
    unsigned short* Ab = &As[0][0];
#pragma unroll
    for (int m = 0; m < 2; ++m)
#pragma unroll
      for (int ni = 0; ni < 2; ++ni) acc[m][ni] = (f32x4){};
#pragma unroll
    for (int kk = 0; kk < 8; ++kk) {
      int so = (((kk*4 + fs) ^ (cl & 7)) << 3);
      bf16x8 a0 = *(const bf16x8*)(&Ab[cl*256 + so]);
      bf16x8 a1 = *(const bf16x8*)(&Ab[(16 + cl)*256 + so]);
#pragma unroll
      for (int ni = 0; ni < 2; ++ni) {
        acc[0][ni] = __builtin_amdgcn_mfma_f32_16x16x32_bf16(a0, bfr[ni][kk], acc[0][ni], 0, 0, 0);
        acc[1][ni] = __builtin_amdgcn_mfma_f32_16x16x32_bf16(a1, bfr[ni][kk], acc[1][ni], 0, 0, 0);
      }
    }
  }

  // ---- main loop: 1 barrier/strip ----
  for (int t = 0; t < 7; ++t) {
    // pre-bar: slab-write(t) (+exp & den on Ek waves), stage As(t+1)
    {
      unsigned short* sb = &slab[t & 1][0];
#pragma unroll
      for (int ni = 0; ni < 2; ++ni) {
        int c = w*32 + ni*16 + cl;
#pragma unroll
        for (int m = 0; m < 2; ++m) {
          int n4 = m*16 + rq;
          ushort4 wv;
          if (!isV) {
            float e0 = __expf(acc[m][ni][0]), e1 = __expf(acc[m][ni][1]);
            float e2 = __expf(acc[m][ni][2]), e3 = __expf(acc[m][ni][3]);
            if (ni == 0) dena0 += (e0 + e1) + (e2 + e3); else dena1 += (e0 + e1) + (e2 + e3);
            wv.x = f2bf(e0); wv.y = f2bf(e1); wv.z = f2bf(e2); wv.w = f2bf(e3);
          } else {
            wv.x = f2bf(acc[m][ni][0]); wv.y = f2bf(acc[m][ni][1]);
            wv.z = f2bf(acc[m][ni][2]); wv.w = f2bf(acc[m][ni][3]);
          }
          *(ushort4*)(&sb[c*40 + n4]) = wv;
        }
      }
    }
    {
      unsigned short* Ab = &As[(t + 1) & 1][0];
      union { ushort4 u4[2]; int4 i4; } pk;
      pk.u4[0].x = f2bf(pa0.x); pk.u4[0].y = f2bf(pa0.y); pk.u4[0].z = f2bf(pa0.z); pk.u4[0].w = f2bf(pa0.w);
      pk.u4[1].x = f2bf(pa1.x); pk.u4[1].y = f2bf(pa1.y); pk.u4[1].z = f2bf(pa1.z); pk.u4[1].w = f2bf(pa1.w);
      *(int4*)(&Ab[aw]) = pk.i4;
    }
    __syncthreads();
    // post-bar: issue next-strip prefetch FIRST (drained only at NEXT barrier)
    if (t < 6) {
      const float* apn = ap + (size_t)(t + 2)*32*256;
      pa0 = *(const float4*)apn;
      pa1 = *(const float4*)(apn + 4);
    }
    // post-bar: ctx-MFMA(t)
    {
      unsigned short* sb = &slab[t & 1][0];
      bf16x8 af0 = *(const bf16x8*)(&sb[ra0]);
      bf16x8 af1 = *(const bf16x8*)(&sb[ra1]);
      bf16x8 bv  = *(const bf16x8*)(&sb[rb]);
      c2[0] = __builtin_amdgcn_mfma_f32_16x16x32_bf16(af0, bv, c2[0], 0, 0, 0);
      c2[1] = __builtin_amdgcn_mfma_f32_16x16x32_bf16(af1, bv, c2[1], 0, 0, 0);
    }
    // post-bar: main-MFMA(t+1)
    {
      unsigned short* Ab = &As[(t + 1) & 1][0];
#pragma unroll
      for (int m = 0; m < 2; ++m)
#pragma unroll
        for (int ni = 0; ni < 2; ++ni) acc[m][ni] = (f32x4){};
#pragma unroll
      for (int kk = 0; kk < 8; ++kk) {
        int so = (((kk*4 + fs) ^ (cl & 7)) << 3);
        bf16x8 a0 = *(const bf16x8*)(&Ab[cl*256 + so]);
        bf16x8 a1 = *(const bf16x8*)(&Ab[(16 + cl)*256 + so]);
#pragma unroll
        for (int ni = 0; ni < 2; ++ni) {
          acc[0][ni] = __builtin_amdgcn_mfma_f32_16x16x32_bf16(a0, bfr[ni][kk], acc[0][ni], 0, 0, 0);
          acc[1][ni] = __builtin_amdgcn_mfma_f32_16x16x32_bf16(a1, bfr[ni][kk], acc[1][ni], 0, 0, 0);
        }
      }
    }
  }
  // ---- tail: strip 7 slab + ctx ----
  {
    unsigned short* sb = &slab[1][0];
#pragma unroll
    for (int ni = 0; ni < 2; ++ni) {
      int c = w*32 + ni*16 + cl;
#pragma unroll
      for (int m = 0; m < 2; ++m) {
        int n4 = m*16 + rq;
        ushort4 wv;
        if (!isV) {
          float e0 = __expf(acc[m][ni][0]), e1 = __expf(acc[m][ni][1]);
          float e2 = __expf(acc[m][ni][2]), e3 = __expf(acc[m][ni][3]);
          if (ni == 0) dena0 += (e0 + e1) + (e2 + e3); else dena1 += (e0 + e1) + (e2 + e3);
          wv.x = f2bf(e0); wv.y = f2bf(e1); wv.z = f2bf(e2); wv.w = f2bf(e3);
        } else {
          wv.x = f2bf(acc[m][ni][0]); wv.y = f2bf(acc[m][ni][1]);
          wv.z = f2bf(acc[m][ni][2]); wv.w = f2bf(acc[m][ni][3]);
        }
        *(ushort4*)(&sb[c*40 + n4]) = wv;
      }
    }
  }
  __syncthreads();
  {
    unsigned short* sb = &slab[1][0];
    bf16x8 af0 = *(const bf16x8*)(&sb[ra0]);
    bf16x8 af1 = *(const bf16x8*)(&sb[ra1]);
    bf16x8 bv  = *(const bf16x8*)(&sb[rb]);
    c2[0] = __builtin_amdgcn_mfma_f32_16x16x32_bf16(af0, bv, c2[0], 0, 0, 0);
    c2[1] = __builtin_amdgcn_mfma_f32_16x16x32_bf16(af1, bv, c2[1], 0, 0, 0);
  }
  // ---- store partials: ctxp[bid][h][d*33 + e], den at e=32 ----
  float* cp = ctxp + ((size_t)bid*8 + h)*1056;
  int ec = isV ? 16 + cl : cl;
#pragma unroll
  for (int di = 0; di < 2; ++di)
#pragma unroll
    for (int r = 0; r < 4; ++r)
      cp[(di*16 + rq + r)*33 + ec] = c2[di][r];
  if (!isV) {
    dena0 += __shfl_xor(dena0, 16); dena0 += __shfl_xor(dena0, 32);
    dena1 += __shfl_xor(dena1, 16); dena1 += __shfl_xor(dena1, 32);
    if (fs == 0) {
      cp[cl*33 + 32]        = dena0;
      cp[(16 + cl)*33 + 32] = dena1;
    }
  }
}

// ---------------- K2b: W2t[bf][c][hd] = sum_e (ctx/den) * Wo ----------------
__global__ __launch_bounds__(256) void k2b_w2(const float* __restrict__ ctxp,
                                              const float* __restrict__ Wo,
                                              unsigned short* __restrict__ W2t) {
  __shared__ float clds[32*33];
  int bid = blockIdx.x;                    // bf*8 + h
  int h = bid & 7, bfi = bid >> 3;
  int tid = threadIdx.x;                   // = c
  for (int i = tid; i < 1056; i += 256) {
    float s = 0.f;
#pragma unroll
    for (int p = 0; p < 16; ++p)
      s += ctxp[((size_t)(bfi*16 + p)*8 + h)*1056 + i];
    clds[i] = s;
  }
  __syncthreads();
  float acc[32] = {};
#pragma unroll 4
  for (int e = 0; e < 32; ++e) {
    float w = Wo[(size_t)(h*32 + e)*256 + tid];
#pragma unroll
    for (int d = 0; d < 32; ++d) acc[d] += clds[d*33 + e] * w;
  }
  unsigned short* o = W2t + ((size_t)bfi*256 + tid)*256 + h*32;
#pragma unroll
  for (int d = 0; d < 32; ++d) o[d] = f2bf(acc[d] / clds[d*33 + 32]);
}

// ---------------- K3s: fused q-proj -> softmax_d -> @W2t -> out ----------------
// Grid 512 x 512thr, 256 rows/block, 8 strips of 32 rows, 1 barrier/strip.
// P1/P2 operand-swapped; prefetch issued post-barrier. (unchanged from r13)
__global__ __launch_bounds__(512, 2) void k3s(const float* __restrict__ x,
                                              const unsigned short* __restrict__ WqT,
                                              const unsigned short* __restrict__ W2t,
                                              float* __restrict__ out) {
  __shared__ unsigned short As[2][32*256];   // 16 KB each, swizzled (32 slots/row)
  __shared__ unsigned short Qs[2][32*256];   // 16 KB each, swizzled
  int bid = blockIdx.x;
  size_t rowbase = (size_t)bid * 256;
  int bfi = bid >> 4;                        // 16 blocks per bf
  int tid = threadIdx.x;
  int lane = tid & 63, wid = tid >> 6;
  int cl = lane & 15, rq = (lane >> 4) << 2, fs = lane >> 4;

  // ---- B panels in registers ----
  bf16x8 bq[2][8], bw[2][8];
#pragma unroll
  for (int nf = 0; nf < 2; ++nf)
#pragma unroll
    for (int kk = 0; kk < 8; ++kk) {
      bq[nf][kk] = *(const bf16x8*)(WqT + (size_t)(wid*32 + nf*16 + cl)*256 + kk*32 + fs*8);
      bw[nf][kk] = *(const bf16x8*)(W2t + ((size_t)bfi*256 + wid*32 + nf*16 + cl)*256 + kk*32 + fs*8);
    }

  int ar = tid >> 5, as_ = tid & 31;
  int aw0 = ar*256 + ((as_ ^ (ar & 7)) << 3);
  int aw1 = (16 + ar)*256 + ((as_ ^ (ar & 7)) << 3);
  const float* ap = x + (rowbase + ar)*256 + as_*8;

  int qslotbase = wid*4 + (rq >> 3);         // + nf*2
  ushort4 qpk[2][2];

  auto stageA = [&](int buf, float4 v0, float4 v1, float4 v2, float4 v3) {
    unsigned short* Ab = &As[buf][0];
    union { ushort4 u4[2]; int4 i4; } pk;
    pk.u4[0].x = f2bf(v0.x); pk.u4[0].y = f2bf(v0.y); pk.u4[0].z = f2bf(v0.z); pk.u4[0].w = f2bf(v0.w);
    pk.u4[1].x = f2bf(v1.x); pk.u4[1].y = f2bf(v1.y); pk.u4[1].z = f2bf(v1.z); pk.u4[1].w = f2bf(v1.w);
    *(int4*)(&Ab[aw0]) = pk.i4;
    pk.u4[0].x = f2bf(v2.x); pk.u4[0].y = f2bf(v2.y); pk.u4[0].z = f2bf(v2.z); pk.u4[0].w = f2bf(v2.w);
    pk.u4[1].x = f2bf(v3.x); pk.u4[1].y = f2bf(v3.y); pk.u4[1].z = f2bf(v3.z); pk.u4[1].w = f2bf(v3.w);
    *(int4*)(&Ab[aw1]) = pk.i4;
  };
  auto p1soft = [&](int buf) {
    unsigned short* Ab = &As[buf][0];
    f32x4 ql[2][2] = {};
#pragma unroll
    for (int kk = 0; kk < 8; ++kk) {
      int so = (((kk*4 + fs) ^ (cl & 7)) << 3);
      bf16x8 a0 = *(const bf16x8*)(&Ab[cl*256 + so]);
      bf16x8 a1 = *(const bf16x8*)(&Ab[(16 + cl)*256 + so]);
#pragma unroll
      for (int nf = 0; nf < 2; ++nf) {
        ql[0][nf] = __builtin_amdgcn_mfma_f32_16x16x32_bf16(bq[nf][kk], a0, ql[0][nf], 0, 0, 0);
        ql[1][nf] = __builtin_amdgcn_mfma_f32_16x16x32_bf16(bq[nf][kk], a1, ql[1][nf], 0, 0, 0);
      }
    }
#pragma unroll
    for (int m = 0; m < 2; ++m) {
      float e0[4], e1[4]; float s8 = 0.f;
#pragma unroll
      for (int r = 0; r < 4; ++r) { e0[r] = __expf(ql[m][0][r]); e1[r] = __expf(ql[m][1][r]); s8 += e0[r] + e1[r]; }
      float s = s8; s += __shfl_xor(s, 16); s += __shfl_xor(s, 32);
      float inv = 1.0f / s;
      qpk[m][0].x = f2bf(e0[0]*inv); qpk[m][0].y = f2bf(e0[1]*inv); qpk[m][0].z = f2bf(e0[2]*inv); qpk[m][0].w = f2bf(e0[3]*inv);
      qpk[m][1].x = f2bf(e1[0]*inv); qpk[m][1].y = f2bf(e1[1]*inv); qpk[m][1].z = f2bf(e1[2]*inv); qpk[m][1].w = f2bf(e1[3]*inv);
    }
  };
  auto qwrite = [&](int buf) {
    unsigned short* Qb = &Qs[buf][0];
#pragma unroll
    for (int m = 0; m < 2; ++m) {
      int row = m*16 + cl;
#pragma unroll
      for (int nf = 0; nf < 2; ++nf) {
        int slot = qslotbase + nf*2;
        *(ushort4*)(&Qb[row*256 + ((slot ^ (row & 7)) << 3) + (rq & 4)]) = qpk[m][nf];
      }
    }
  };

  float4 pa0 = *(const float4*)ap;
  float4 pa1 = *(const float4*)(ap + 4);
  float4 pa2 = *(const float4*)(ap + 16*256);
  float4 pa3 = *(const float4*)(ap + 16*256 + 4);
  stageA(0, pa0, pa1, pa2, pa3);
  {
    const float* apn = ap + 32*256;
    pa0 = *(const float4*)apn;
    pa1 = *(const float4*)(apn + 4);
    pa2 = *(const float4*)(apn + 16*256);
    pa3 = *(const float4*)(apn + 16*256 + 4);
  }
  __syncthreads();
  p1soft(0);

  for (int t = 0; t < 7; ++t) {
    // pre-bar: stage As(t+1) from regs, write Qs(t)
    stageA((t + 1) & 1, pa0, pa1, pa2, pa3);
    qwrite(t & 1);
    __syncthreads();
    // post-bar: issue prefetch(t+2) first (drained only at NEXT barrier)
    if (t < 6) {
      const float* apn = ap + (size_t)(t + 2)*32*256;
      pa0 = *(const float4*)apn;
      pa1 = *(const float4*)(apn + 4);
      pa2 = *(const float4*)(apn + 16*256);
      pa3 = *(const float4*)(apn + 16*256 + 4);
    }
    // P2(t)
    f32x4 oa[2][2] = {};
    {
      unsigned short* Qb = &Qs[t & 1][0];
#pragma unroll
      for (int kk = 0; kk < 8; ++kk) {
        int so = (((kk*4 + fs) ^ (cl & 7)) << 3);
        bf16x8 q0 = *(const bf16x8*)(&Qb[cl*256 + so]);
        bf16x8 q1 = *(const bf16x8*)(&Qb[(16 + cl)*256 + so]);
#pragma unroll
        for (int nf = 0; nf < 2; ++nf) {
          oa[0][nf] = __builtin_amdgcn_mfma_f32_16x16x32_bf16(bw[nf][kk], q0, oa[0][nf], 0, 0, 0);
          oa[1][nf] = __builtin_amdgcn_mfma_f32_16x16x32_bf16(bw[nf][kk], q1, oa[1][nf], 0, 0, 0);
        }
      }
    }
    // P1(t+1) + softmax(t+1)
    p1soft((t + 1) & 1);
    // out(t): float4 stores
#pragma unroll
    for (int m = 0; m < 2; ++m)
#pragma unroll
      for (int nf = 0; nf < 2; ++nf)
        *(f32x4*)(&out[(rowbase + (size_t)t*32 + m*16 + cl)*256 + wid*32 + nf*16 + rq]) = oa[m][nf];
  }
  // ---- tail: strip 7 ----
  qwrite(1);
  __syncthreads();
  {
    unsigned short* Qb = &Qs[1][0];
    f32x4 oa[2][2] = {};
#pragma unroll
    for (int kk = 0; kk < 8; ++kk) {
      int so = (((kk*4 + fs) ^ (cl & 7)) << 3);
      bf16x8 q0 = *(const bf16x8*)(&Qb[cl*256 + so]);
      bf16x8 q1 = *(const bf16x8*)(&Qb[(16 + cl)*256 + so]);
#pragma unroll
      for (int nf = 0; nf < 2; ++nf) {
        oa[0][nf] = __builtin_amdgcn_mfma_f32_16x16x32_bf16(bw[nf][kk], q0, oa[0][nf], 0, 0, 0);
        oa[1][nf] = __builtin_amdgcn_mfma_f32_16x16x32_bf16(bw[nf][kk], q1, oa[1][nf], 0, 0, 0);
      }
    }
#pragma unroll
    for (int m = 0; m < 2; ++m)
#pragma unroll
      for (int nf = 0; nf < 2; ++nf)
        *(f32x4*)(&out[(rowbase + (size_t)7*32 + m*16 + cl)*256 + wid*32 + nf*16 + rq]) = oa[m][nf];
  }
}

extern "C" void kernel_launch(void* const* d_in, const int* in_sizes, int n_in,
                              void* d_out, int out_size, void* d_ws, size_t ws_size,
                              hipStream_t stream) {
  const float* x  = (const float*)d_in[0];
  const float* Wq = (const float*)d_in[1];
  const float* Wk = (const float*)d_in[2];
  const float* Wv = (const float*)d_in[3];
  const float* Wo = (const float*)d_in[4];
  float* out = (float*)d_out;

  // ws layout: WkvT (131072 ush) | WqT (65536 ush) | W2t (2097152 ush) | ctxp (512*8*1056 f32)
  unsigned short* WkvT = (unsigned short*)d_ws;
  unsigned short* WqT  = WkvT + 131072;
  unsigned short* W2t  = WqT  + 65536;
  float*          ctxp = (float*)(W2t + 2097152);

  k0_prep <<<768,  256,  0, stream>>>(Wq, Wk, Wv, WqT, WkvT);
  k1w     <<<512,  1024, 0, stream>>>(x, WkvT, ctxp);
  k2b_w2  <<<256,  256,  0, stream>>>(ctxp, Wo, W2t);
  k3s     <<<512,  512,  0, stream>>>(x, WqT, W2t, out);
}

// Round 16
// 131.290 us; speedup vs baseline: 1.0956x; 1.0563x over previous
//
#include <hip/hip_runtime.h>
#include <hip/hip_bf16.h>

// SpatialLinearAttention: b=2,f=16,h=w=64,c=256, heads=8, D=32
// BF=32 fused batch, n=4096, hD=256.
// out[n,c] = sum_hd softmax_d(xWq)[n,hd] * W2[hd,c]
// W2[hd,c] = sum_e (ctx[h,d,e]/den[h,d]) * Wo[h*32+e,c]
// ctx[h,d,e] = sum_n exp(xWk)[n,h*32+d] * (xWv)[n,h*32+e];  den = sum_n exp(xWk)
// k1w: fused kv-proj + ctx. 256 blocks x 512 rows (16 strips): 1 dispatch round,
//      half the prologues vs 512x256. Slab stride 40 no-XOR, 1 bar/strip,
//      post-bar prefetch, asm-pinned B-frags.
// k3s: fused q-proj + softmax + @W2t (unchanged).

typedef __attribute__((ext_vector_type(8))) short bf16x8;
typedef __attribute__((ext_vector_type(4))) float f32x4;

__device__ __forceinline__ unsigned short f2bf(float x) {
  __hip_bfloat16 h = __float2bfloat16(x);          // HW v_cvt (RNE), 1 VALU op
  union { __hip_bfloat16 b; unsigned short u; } c; c.b = h; return c.u;
}

// ---------------- K0: transpose & convert weights to [N][K] bf16 ----------------
__global__ __launch_bounds__(256) void k0_prep(const float* __restrict__ Wq,
                                               const float* __restrict__ Wk,
                                               const float* __restrict__ Wv,
                                               unsigned short* __restrict__ WqT,
                                               unsigned short* __restrict__ WkvT) {
  int r = blockIdx.x, c = threadIdx.x;
  if (r < 256)      WqT [(r      )*256 + c] = f2bf(Wq[c*256 + r]);
  else if (r < 512) WkvT[(r - 256)*256 + c] = f2bf(Wk[c*256 + (r-256)]);
  else              WkvT[(r - 256)*256 + c] = f2bf(Wv[c*256 + (r-512)]);
}

// ---------------- K1w: fused kv-proj GEMM + exp + ctx reduction ----------------
// Grid 256 x 1024thr (16 waves). Block: 512 rows x 512 cols; wave w owns cols
// [w*32, w*32+32) of [Ek|V] (w<8: Ek logits+exp, w>=8: V). 16 strips of 32 rows,
// 1 barrier/strip. Slab [c][n] stride 40 ushorts, no XOR. B-frags pinned.
__global__ __launch_bounds__(1024, 4) void k1w(const float* __restrict__ x,
                                               const unsigned short* __restrict__ WkvT,
                                               float* __restrict__ ctxp) {
  __shared__ unsigned short As[2][32*256];    // 16 KB each, swizzled (32 slots/row)
  __shared__ unsigned short slab[2][512*40];  // 40 KB each: C^T [c][n], padded
  int bid = blockIdx.x;
  size_t rowbase = (size_t)bid * 512;
  int tid = threadIdx.x;
  int lane = tid & 63, w = tid >> 6;
  int cl = lane & 15, rq = (lane >> 4) << 2, fs = lane >> 4;
  int h = w & 7;
  bool isV = w >= 8;

  // ---- B fragments in registers: rows w*32..w*32+32 of WkvT ----
  bf16x8 bfr[2][8];
#pragma unroll
  for (int ni = 0; ni < 2; ++ni)
#pragma unroll
    for (int kk = 0; kk < 8; ++kk)
      bfr[ni][kk] = *(const bf16x8*)(WkvT + (size_t)(w*32 + ni*16 + cl)*256 + kk*32 + fs*8);
  // PIN: defeat remat so the B-panel is truly register-resident across strips.
#pragma unroll
  for (int ni = 0; ni < 2; ++ni)
#pragma unroll
    for (int kk = 0; kk < 8; ++kk)
      asm volatile("" : "+v"(bfr[ni][kk]));

  // ---- ctx accumulators: head h, e-half per wave ----
  f32x4 c2[2] = {};
  float dena0 = 0.f, dena1 = 0.f;            // den partials (w<8 only)

  // ---- A staging map: 1024 thr = 32 rows x 32 slots ----
  int ar = tid >> 5, as_ = tid & 31;
  int aw = ar*256 + ((as_ ^ (ar & 7)) << 3);
  const float* ap = x + (rowbase + ar)*256 + as_*8;

  // slab read addrs for ctx (constant), stride 40, no XOR
  int ca0 = h*32 + cl, ca1 = h*32 + 16 + cl;
  int cb  = 256 + h*32 + (isV ? 16 : 0) + cl;
  int ra0 = ca0*40 + fs*8;
  int ra1 = ca1*40 + fs*8;
  int rb  = cb*40  + fs*8;

  f32x4 acc[2][2];

  auto stageA = [&](int buf, float4 v0, float4 v1) {
    unsigned short* Ab = &As[buf][0];
    union { ushort4 u4[2]; int4 i4; } pk;
    pk.u4[0].x = f2bf(v0.x); pk.u4[0].y = f2bf(v0.y); pk.u4[0].z = f2bf(v0.z); pk.u4[0].w = f2bf(v0.w);
    pk.u4[1].x = f2bf(v1.x); pk.u4[1].y = f2bf(v1.y); pk.u4[1].z = f2bf(v1.z); pk.u4[1].w = f2bf(v1.w);
    *(int4*)(&Ab[aw]) = pk.i4;
  };
  auto mainMFMA = [&](int buf) {
    unsigned short* Ab = &As[buf][0];
#pragma unroll
    for (int m = 0; m < 2; ++m)
#pragma unroll
      for (int ni = 0; ni < 2; ++ni) acc[m][ni] = (f32x4){};
#pragma unroll
    for (int kk = 0; kk < 8; ++kk) {
      int so = (((kk*4 + fs) ^ (cl & 7)) << 3);
      bf16x8 a0 = *(const bf16x8*)(&Ab[cl*256 + so]);
      bf16x8 a1 = *(const bf16x8*)(&Ab[(16 + cl)*256 + so]);
#pragma unroll
      for (int ni = 0; ni < 2; ++ni) {
        acc[0][ni] = __builtin_amdgcn_mfma_f32_16x16x32_bf16(a0, bfr[ni][kk], acc[0][ni], 0, 0, 0);
        acc[1][ni] = __builtin_amdgcn_mfma_f32_16x16x32_bf16(a1, bfr[ni][kk], acc[1][ni], 0, 0, 0);
      }
    }
  };
  auto slabWrite = [&](int buf) {
    unsigned short* sb = &slab[buf][0];
#pragma unroll
    for (int ni = 0; ni < 2; ++ni) {
      int c = w*32 + ni*16 + cl;
#pragma unroll
      for (int m = 0; m < 2; ++m) {
        int n4 = m*16 + rq;
        ushort4 wv;
        if (!isV) {
          float e0 = __expf(acc[m][ni][0]), e1 = __expf(acc[m][ni][1]);
          float e2 = __expf(acc[m][ni][2]), e3 = __expf(acc[m][ni][3]);
          if (ni == 0) dena0 += (e0 + e1) + (e2 + e3); else dena1 += (e0 + e1) + (e2 + e3);
          wv.x = f2bf(e0); wv.y = f2bf(e1); wv.z = f2bf(e2); wv.w = f2bf(e3);
        } else {
          wv.x = f2bf(acc[m][ni][0]); wv.y = f2bf(acc[m][ni][1]);
          wv.z = f2bf(acc[m][ni][2]); wv.w = f2bf(acc[m][ni][3]);
        }
        *(ushort4*)(&sb[c*40 + n4]) = wv;
      }
    }
  };
  auto ctxMFMA = [&](int buf) {
    unsigned short* sb = &slab[buf][0];
    bf16x8 af0 = *(const bf16x8*)(&sb[ra0]);
    bf16x8 af1 = *(const bf16x8*)(&sb[ra1]);
    bf16x8 bv  = *(const bf16x8*)(&sb[rb]);
    c2[0] = __builtin_amdgcn_mfma_f32_16x16x32_bf16(af0, bv, c2[0], 0, 0, 0);
    c2[1] = __builtin_amdgcn_mfma_f32_16x16x32_bf16(af1, bv, c2[1], 0, 0, 0);
  };

  // ---- prologue: stage strip 0, prefetch strip 1 ----
  float4 pa0 = *(const float4*)ap;
  float4 pa1 = *(const float4*)(ap + 4);
  stageA(0, pa0, pa1);
  {
    const float* apn = ap + 32*256;
    pa0 = *(const float4*)apn;
    pa1 = *(const float4*)(apn + 4);
  }
  __syncthreads();
  mainMFMA(0);

  // ---- main loop: 16 strips, 1 barrier/strip ----
  for (int t = 0; t < 15; ++t) {
    slabWrite(t & 1);                        // acc(t) -> slab (+exp/den)
    stageA((t + 1) & 1, pa0, pa1);
    __syncthreads();
    // post-bar: issue next-strip prefetch FIRST (drained only at NEXT barrier)
    if (t < 14) {
      const float* apn = ap + (size_t)(t + 2)*32*256;
      pa0 = *(const float4*)apn;
      pa1 = *(const float4*)(apn + 4);
    }
    ctxMFMA(t & 1);                          // reads slab(t)
    mainMFMA((t + 1) & 1);                   // acc(t+1)
  }
  // ---- tail: strip 15 slab + ctx ----
  slabWrite(1);
  __syncthreads();
  ctxMFMA(1);

  // ---- store partials: ctxp[bid][h][d*33 + e], den at e=32 ----
  float* cp = ctxp + ((size_t)bid*8 + h)*1056;
  int ec = isV ? 16 + cl : cl;
#pragma unroll
  for (int di = 0; di < 2; ++di)
#pragma unroll
    for (int r = 0; r < 4; ++r)
      cp[(di*16 + rq + r)*33 + ec] = c2[di][r];
  if (!isV) {
    dena0 += __shfl_xor(dena0, 16); dena0 += __shfl_xor(dena0, 32);
    dena1 += __shfl_xor(dena1, 16); dena1 += __shfl_xor(dena1, 32);
    if (fs == 0) {
      cp[cl*33 + 32]        = dena0;
      cp[(16 + cl)*33 + 32] = dena1;
    }
  }
}

// ---------------- K2b: W2t[bf][c][hd] = sum_e (ctx/den) * Wo ----------------
__global__ __launch_bounds__(256) void k2b_w2(const float* __restrict__ ctxp,
                                              const float* __restrict__ Wo,
                                              unsigned short* __restrict__ W2t) {
  __shared__ float clds[32*33];
  int bid = blockIdx.x;                    // bf*8 + h
  int h = bid & 7, bfi = bid >> 3;
  int tid = threadIdx.x;                   // = c
  for (int i = tid; i < 1056; i += 256) {
    float s = 0.f;
#pragma unroll
    for (int p = 0; p < 8; ++p)            // 8 row-chunks of 512 per bf
      s += ctxp[((size_t)(bfi*8 + p)*8 + h)*1056 + i];
    clds[i] = s;
  }
  __syncthreads();
  float acc[32] = {};
#pragma unroll 4
  for (int e = 0; e < 32; ++e) {
    float w = Wo[(size_t)(h*32 + e)*256 + tid];
#pragma unroll
    for (int d = 0; d < 32; ++d) acc[d] += clds[d*33 + e] * w;
  }
  unsigned short* o = W2t + ((size_t)bfi*256 + tid)*256 + h*32;
#pragma unroll
  for (int d = 0; d < 32; ++d) o[d] = f2bf(acc[d] / clds[d*33 + 32]);
}

// ---------------- K3s: fused q-proj -> softmax_d -> @W2t -> out ----------------
// Grid 512 x 512thr, 256 rows/block, 8 strips of 32 rows, 1 barrier/strip.
// P1/P2 operand-swapped; prefetch issued post-barrier.
__global__ __launch_bounds__(512, 2) void k3s(const float* __restrict__ x,
                                              const unsigned short* __restrict__ WqT,
                                              const unsigned short* __restrict__ W2t,
                                              float* __restrict__ out) {
  __shared__ unsigned short As[2][32*256];   // 16 KB each, swizzled (32 slots/row)
  __shared__ unsigned short Qs[2][32*256];   // 16 KB each, swizzled
  int bid = blockIdx.x;
  size_t rowbase = (size_t)bid * 256;
  int bfi = bid >> 4;                        // 16 blocks per bf
  int tid = threadIdx.x;
  int lane = tid & 63, wid = tid >> 6;
  int cl = lane & 15, rq = (lane >> 4) << 2, fs = lane >> 4;

  // ---- B panels in registers ----
  bf16x8 bq[2][8], bw[2][8];
#pragma unroll
  for (int nf = 0; nf < 2; ++nf)
#pragma unroll
    for (int kk = 0; kk < 8; ++kk) {
      bq[nf][kk] = *(const bf16x8*)(WqT + (size_t)(wid*32 + nf*16 + cl)*256 + kk*32 + fs*8);
      bw[nf][kk] = *(const bf16x8*)(W2t + ((size_t)bfi*256 + wid*32 + nf*16 + cl)*256 + kk*32 + fs*8);
    }

  int ar = tid >> 5, as_ = tid & 31;
  int aw0 = ar*256 + ((as_ ^ (ar & 7)) << 3);
  int aw1 = (16 + ar)*256 + ((as_ ^ (ar & 7)) << 3);
  const float* ap = x + (rowbase + ar)*256 + as_*8;

  int qslotbase = wid*4 + (rq >> 3);         // + nf*2
  ushort4 qpk[2][2];

  auto stageA = [&](int buf, float4 v0, float4 v1, float4 v2, float4 v3) {
    unsigned short* Ab = &As[buf][0];
    union { ushort4 u4[2]; int4 i4; } pk;
    pk.u4[0].x = f2bf(v0.x); pk.u4[0].y = f2bf(v0.y); pk.u4[0].z = f2bf(v0.z); pk.u4[0].w = f2bf(v0.w);
    pk.u4[1].x = f2bf(v1.x); pk.u4[1].y = f2bf(v1.y); pk.u4[1].z = f2bf(v1.z); pk.u4[1].w = f2bf(v1.w);
    *(int4*)(&Ab[aw0]) = pk.i4;
    pk.u4[0].x = f2bf(v2.x); pk.u4[0].y = f2bf(v2.y); pk.u4[0].z = f2bf(v2.z); pk.u4[0].w = f2bf(v2.w);
    pk.u4[1].x = f2bf(v3.x); pk.u4[1].y = f2bf(v3.y); pk.u4[1].z = f2bf(v3.z); pk.u4[1].w = f2bf(v3.w);
    *(int4*)(&Ab[aw1]) = pk.i4;
  };
  auto p1soft = [&](int buf) {
    unsigned short* Ab = &As[buf][0];
    f32x4 ql[2][2] = {};
#pragma unroll
    for (int kk = 0; kk < 8; ++kk) {
      int so = (((kk*4 + fs) ^ (cl & 7)) << 3);
      bf16x8 a0 = *(const bf16x8*)(&Ab[cl*256 + so]);
      bf16x8 a1 = *(const bf16x8*)(&Ab[(16 + cl)*256 + so]);
#pragma unroll
      for (int nf = 0; nf < 2; ++nf) {
        ql[0][nf] = __builtin_amdgcn_mfma_f32_16x16x32_bf16(bq[nf][kk], a0, ql[0][nf], 0, 0, 0);
        ql[1][nf] = __builtin_amdgcn_mfma_f32_16x16x32_bf16(bq[nf][kk], a1, ql[1][nf], 0, 0, 0);
      }
    }
#pragma unroll
    for (int m = 0; m < 2; ++m) {
      float e0[4], e1[4]; float s8 = 0.f;
#pragma unroll
      for (int r = 0; r < 4; ++r) { e0[r] = __expf(ql[m][0][r]); e1[r] = __expf(ql[m][1][r]); s8 += e0[r] + e1[r]; }
      float s = s8; s += __shfl_xor(s, 16); s += __shfl_xor(s, 32);
      float inv = 1.0f / s;
      qpk[m][0].x = f2bf(e0[0]*inv); qpk[m][0].y = f2bf(e0[1]*inv); qpk[m][0].z = f2bf(e0[2]*inv); qpk[m][0].w = f2bf(e0[3]*inv);
      qpk[m][1].x = f2bf(e1[0]*inv); qpk[m][1].y = f2bf(e1[1]*inv); qpk[m][1].z = f2bf(e1[2]*inv); qpk[m][1].w = f2bf(e1[3]*inv);
    }
  };
  auto qwrite = [&](int buf) {
    unsigned short* Qb = &Qs[buf][0];
#pragma unroll
    for (int m = 0; m < 2; ++m) {
      int row = m*16 + cl;
#pragma unroll
      for (int nf = 0; nf < 2; ++nf) {
        int slot = qslotbase + nf*2;
        *(ushort4*)(&Qb[row*256 + ((slot ^ (row & 7)) << 3) + (rq & 4)]) = qpk[m][nf];
      }
    }
  };

  float4 pa0 = *(const float4*)ap;
  float4 pa1 = *(const float4*)(ap + 4);
  float4 pa2 = *(const float4*)(ap + 16*256);
  float4 pa3 = *(const float4*)(ap + 16*256 + 4);
  stageA(0, pa0, pa1, pa2, pa3);
  {
    const float* apn = ap + 32*256;
    pa0 = *(const float4*)apn;
    pa1 = *(const float4*)(apn + 4);
    pa2 = *(const float4*)(apn + 16*256);
    pa3 = *(const float4*)(apn + 16*256 + 4);
  }
  __syncthreads();
  p1soft(0);

  for (int t = 0; t < 7; ++t) {
    // pre-bar: stage As(t+1) from regs, write Qs(t)
    stageA((t + 1) & 1, pa0, pa1, pa2, pa3);
    qwrite(t & 1);
    __syncthreads();
    // post-bar: issue prefetch(t+2) first (drained only at NEXT barrier)
    if (t < 6) {
      const float* apn = ap + (size_t)(t + 2)*32*256;
      pa0 = *(const float4*)apn;
      pa1 = *(const float4*)(apn + 4);
      pa2 = *(const float4*)(apn + 16*256);
      pa3 = *(const float4*)(apn + 16*256 + 4);
    }
    // P2(t)
    f32x4 oa[2][2] = {};
    {
      unsigned short* Qb = &Qs[t & 1][0];
#pragma unroll
      for (int kk = 0; kk < 8; ++kk) {
        int so = (((kk*4 + fs) ^ (cl & 7)) << 3);
        bf16x8 q0 = *(const bf16x8*)(&Qb[cl*256 + so]);
        bf16x8 q1 = *(const bf16x8*)(&Qb[(16 + cl)*256 + so]);
#pragma unroll
        for (int nf = 0; nf < 2; ++nf) {
          oa[0][nf] = __builtin_amdgcn_mfma_f32_16x16x32_bf16(bw[nf][kk], q0, oa[0][nf], 0, 0, 0);
          oa[1][nf] = __builtin_amdgcn_mfma_f32_16x16x32_bf16(bw[nf][kk], q1, oa[1][nf], 0, 0, 0);
        }
      }
    }
    // P1(t+1) + softmax(t+1)
    p1soft((t + 1) & 1);
    // out(t): float4 stores
#pragma unroll
    for (int m = 0; m < 2; ++m)
#pragma unroll
      for (int nf = 0; nf < 2; ++nf)
        *(f32x4*)(&out[(rowbase + (size_t)t*32 + m*16 + cl)*256 + wid*32 + nf*16 + rq]) = oa[m][nf];
  }
  // ---- tail: strip 7 ----
  qwrite(1);
  __syncthreads();
  {
    unsigned short* Qb = &Qs[1][0];
    f32x4 oa[2][2] = {};
#pragma unroll
    for (int kk = 0; kk < 8; ++kk) {
      int so = (((kk*4 + fs) ^ (cl & 7)) << 3);
      bf16x8 q0 = *(const bf16x8*)(&Qb[cl*256 + so]);
      bf16x8 q1 = *(const bf16x8*)(&Qb[(16 + cl)*256 + so]);
#pragma unroll
      for (int nf = 0; nf < 2; ++nf) {
        oa[0][nf] = __builtin_amdgcn_mfma_f32_16x16x32_bf16(bw[nf][kk], q0, oa[0][nf], 0, 0, 0);
        oa[1][nf] = __builtin_amdgcn_mfma_f32_16x16x32_bf16(bw[nf][kk], q1, oa[1][nf], 0, 0, 0);
      }
    }
#pragma unroll
    for (int m = 0; m < 2; ++m)
#pragma unroll
      for (int nf = 0; nf < 2; ++nf)
        *(f32x4*)(&out[(rowbase + (size_t)7*32 + m*16 + cl)*256 + wid*32 + nf*16 + rq]) = oa[m][nf];
  }
}

extern "C" void kernel_launch(void* const* d_in, const int* in_sizes, int n_in,
                              void* d_out, int out_size, void* d_ws, size_t ws_size,
                              hipStream_t stream) {
  const float* x  = (const float*)d_in[0];
  const float* Wq = (const float*)d_in[1];
  const float* Wk = (const float*)d_in[2];
  const float* Wv = (const float*)d_in[3];
  const float* Wo = (const float*)d_in[4];
  float* out = (float*)d_out;

  // ws layout: WkvT (131072 ush) | WqT (65536 ush) | W2t (2097152 ush) | ctxp (256*8*1056 f32)
  unsigned short* WkvT = (unsigned short*)d_ws;
  unsigned short* WqT  = WkvT + 131072;
  unsigned short* W2t  = WqT  + 65536;
  float*          ctxp = (float*)(W2t + 2097152);

  k0_prep <<<768,  256,  0, stream>>>(Wq, Wk, Wv, WqT, WkvT);
  k1w     <<<256,  1024, 0, stream>>>(x, WkvT, ctxp);
  k2b_w2  <<<256,  256,  0, stream>>>(ctxp, Wo, W2t);
  k3s     <<<512,  512,  0, stream>>>(x, WqT, W2t, out);
}